// Round 1
// baseline (48.437 us; speedup 1.0000x reference)
//
#include <hip/hip_runtime.h>

#define NHEADS 16
#define KSZ 7
#define TLEN 4096
#define TV (TLEN / 4)   // 1024 float4 per row

__global__ __launch_bounds__(256) void lightconv_kernel(
    const float* __restrict__ x, const float* __restrict__ weight,
    float* __restrict__ out, int n4)
{
    int g = blockIdx.x * 256 + threadIdx.x;
    if (g >= n4) return;

    int row = g >> 10;          // g / TV
    int q   = g & (TV - 1);     // float4 index within row
    int h   = row & (NHEADS - 1);

    // softmax over the 7 weights of this head (head is uniform per block,
    // so these loads are broadcast / L1 hits; cost hidden under memory time)
    float w[KSZ];
    float m = -1e30f;
    #pragma unroll
    for (int k = 0; k < KSZ; ++k) {
        w[k] = weight[h * KSZ + k];
        m = fmaxf(m, w[k]);
    }
    float s = 0.f;
    #pragma unroll
    for (int k = 0; k < KSZ; ++k) {
        w[k] = expf(w[k] - m);
        s += w[k];
    }
    float inv = 1.0f / s;
    #pragma unroll
    for (int k = 0; k < KSZ; ++k) w[k] *= inv;

    const float4* x4 = (const float4*)x;
    float4 cur  = x4[g];
    float4 prev = make_float4(0.f, 0.f, 0.f, 0.f);
    float4 next = make_float4(0.f, 0.f, 0.f, 0.f);
    if (q > 0)      prev = x4[g - 1];   // zero-pad at row start
    if (q < TV - 1) next = x4[g + 1];   // zero-pad at row end

    // window e[j] = in[p - 3 + j], p = 4*q
    float e[10] = { prev.y, prev.z, prev.w,
                    cur.x,  cur.y,  cur.z,  cur.w,
                    next.x, next.y, next.z };

    float r[4];
    #pragma unroll
    for (int i = 0; i < 4; ++i) {
        float acc = 0.f;
        #pragma unroll
        for (int k = 0; k < KSZ; ++k)
            acc = fmaf(w[k], e[i + k], acc);
        r[i] = acc;
    }

    ((float4*)out)[g] = make_float4(r[0], r[1], r[2], r[3]);
}

extern "C" void kernel_launch(void* const* d_in, const int* in_sizes, int n_in,
                              void* d_out, int out_size, void* d_ws, size_t ws_size,
                              hipStream_t stream) {
    const float* x = (const float*)d_in[0];
    const float* w = (const float*)d_in[1];
    float* out = (float*)d_out;

    int n4 = out_size / 4;                 // 33554432 / 4 = 8388608 float4s
    dim3 grid((n4 + 255) / 256);
    dim3 block(256);
    lightconv_kernel<<<grid, block, 0, stream>>>(x, w, out, n4);
}

// Round 3
// 45.229 us; speedup vs baseline: 1.0709x; 1.0709x over previous
//
#include <hip/hip_runtime.h>

#define NHEADS 16
#define KSZ 7
#define TLEN 4096
#define TV8 (TLEN / 8)   // 512 8-float chunks per row

typedef float floatx4 __attribute__((ext_vector_type(4)));

__global__ __launch_bounds__(256) void lightconv_kernel(
    const float* __restrict__ x, const float* __restrict__ weight,
    float* __restrict__ out, int n8)
{
    int g = blockIdx.x * 256 + threadIdx.x;
    if (g >= n8) return;

    int row = g >> 9;           // g / TV8
    int q   = g & (TV8 - 1);    // 8-float chunk index within row
    int h   = row & (NHEADS - 1);

    // softmax over the 7 weights of this head (uniform per wave -> broadcast)
    float w[KSZ];
    float m = -1e30f;
    #pragma unroll
    for (int k = 0; k < KSZ; ++k) {
        w[k] = weight[h * KSZ + k];
        m = fmaxf(m, w[k]);
    }
    float s = 0.f;
    #pragma unroll
    for (int k = 0; k < KSZ; ++k) {
        w[k] = expf(w[k] - m);
        s += w[k];
    }
    float inv = 1.0f / s;
    #pragma unroll
    for (int k = 0; k < KSZ; ++k) w[k] *= inv;

    const floatx4* x4 = (const floatx4*)x;
    int b = g << 1;  // index of first float4 of this chunk
    floatx4 cur0 = x4[b];
    floatx4 cur1 = x4[b + 1];
    floatx4 prev = (floatx4)(0.f);
    floatx4 next = (floatx4)(0.f);
    if (q > 0)       prev = x4[b - 1];   // zero-pad at row start
    if (q < TV8 - 1) next = x4[b + 2];   // zero-pad at row end

    // window e[j] = in[8*q - 3 + j], j = 0..13
    float e[14] = { prev.y, prev.z, prev.w,
                    cur0.x, cur0.y, cur0.z, cur0.w,
                    cur1.x, cur1.y, cur1.z, cur1.w,
                    next.x, next.y, next.z };

    float r[8];
    #pragma unroll
    for (int i = 0; i < 8; ++i) {
        float acc = 0.f;
        #pragma unroll
        for (int k = 0; k < KSZ; ++k)
            acc = fmaf(w[k], e[i + k], acc);
        r[i] = acc;
    }

    floatx4* o4 = (floatx4*)out;
    floatx4 r0 = { r[0], r[1], r[2], r[3] };
    floatx4 r1 = { r[4], r[5], r[6], r[7] };
    __builtin_nontemporal_store(r0, &o4[b]);
    __builtin_nontemporal_store(r1, &o4[b + 1]);
}

extern "C" void kernel_launch(void* const* d_in, const int* in_sizes, int n_in,
                              void* d_out, int out_size, void* d_ws, size_t ws_size,
                              hipStream_t stream) {
    const float* x = (const float*)d_in[0];
    const float* w = (const float*)d_in[1];
    float* out = (float*)d_out;

    int n8 = out_size / 8;                 // 33554432 / 8 = 4194304 chunks
    dim3 grid((n8 + 255) / 256);
    dim3 block(256);
    lightconv_kernel<<<grid, block, 0, stream>>>(x, w, out, n8);
}